// Round 2
// 1010.121 us; speedup vs baseline: 1.1950x; 1.1950x over previous
//
#include <hip/hip_runtime.h>
#include <hip/hip_bf16.h>

typedef unsigned short u16;
typedef __attribute__((ext_vector_type(8))) short short8;
typedef __attribute__((ext_vector_type(4))) float f32x4;

#define BB 8
#define LL 1024
#define DD 768
#define DD2 1536
#define BL 8192           // B*L
#define LD 786432         // L*D elements per sample

__device__ __forceinline__ float bf2f(u16 u) {
    return __uint_as_float(((unsigned int)u) << 16);
}
__device__ __forceinline__ u16 f2b(float f) {
    __hip_bfloat16 h = __float2bfloat16(f);
    return *reinterpret_cast<u16*>(&h);
}
// dual-dtype input load: f32 ? fp32 array : bf16 array
__device__ __forceinline__ float ldin(const void* p, size_t i, int f32) {
    return f32 ? ((const float*)p)[i] : bf2f(((const u16*)p)[i]);
}
__device__ __forceinline__ float siluf(float x) { return x / (1.f + expf(-x)); }
__device__ __forceinline__ float softplusf(float x) { return (x > 20.f) ? x : log1pf(expf(x)); }

// async global->LDS, 16B per lane; LDS dest = wave-uniform base + lane*16
__device__ __forceinline__ void async_load16(const u16* g, u16* l) {
    __builtin_amdgcn_global_load_lds(
        (const __attribute__((address_space(1))) unsigned int*)g,
        (__attribute__((address_space(3))) unsigned int*)l, 16, 0, 0);
}

// ---------------- dtype detect (float width on emb, int width on ids) --------------
__global__ void detect_kernel(const void* emb, const int* ids, int* flag, float* stats) {
    __shared__ int cnt, nz;
    if (threadIdx.x == 0) { cnt = 0; nz = 0; }
    __syncthreads();
    const u16* p = (const u16*)emb;
    int lc = 0, ln = 0;
    for (int k = threadIdx.x; k < 4096; k += 256) {
        int e = (p[2 * k] >> 7) & 0xFF;
        if (e >= 90 && e <= 130) lc++;
        if (ids[2 * k + 1] != 0) ln++;
    }
    atomicAdd(&cnt, lc);
    atomicAdd(&nz, ln);
    __syncthreads();
    if (threadIdx.x == 0) {
        flag[0] = (cnt < 2048) ? 1 : 0;   // 1 = floats are fp32
        flag[1] = (nz < 8) ? 1 : 0;       // 1 = ids are int64
    }
    if (threadIdx.x < 16) stats[threadIdx.x] = 0.f;
}

// ---------------- diagnostic fill (ws too small): error print reveals ws MB ---------
__global__ void diag_kernel(u16* out, int n, float val) {
    int i = blockIdx.x * 256 + threadIdx.x;
    if (i < n) out[i] = f2b(val);
}

// ---------------- weight convert: Wt[n][k] = (bf16) W[k][n] -------------------------
__global__ __launch_bounds__(256) void wt_convert(const void* __restrict__ W,
                                                  u16* __restrict__ Wt,
                                                  int K, int N,
                                                  const int* __restrict__ flagp) {
    const int f32 = flagp[0];
    __shared__ float t[32][33];
    int n0 = blockIdx.x * 32, k0 = blockIdx.y * 32;
    int c = threadIdx.x & 31, r4 = threadIdx.x >> 5;
    #pragma unroll
    for (int rr = 0; rr < 4; rr++) {
        int r = r4 * 4 + rr;
        t[r][c] = ldin(W, (size_t)(k0 + r) * N + n0 + c, f32);
    }
    __syncthreads();
    #pragma unroll
    for (int rr = 0; rr < 4; rr++) {
        int r = r4 * 4 + rr;
        Wt[(size_t)(n0 + r) * K + k0 + c] = f2b(t[c][r]);
    }
}

// ---------------- conv weight: Wc[o][k*1024+i] = (bf16) conv_w[o][i][k] -------------
__global__ __launch_bounds__(256) void convw_convert(const void* __restrict__ cw,
                                                     u16* __restrict__ Wc,
                                                     const int* __restrict__ flagp) {
    const int f32 = flagp[0];
    size_t idx = (size_t)blockIdx.x * 256 + threadIdx.x;   // < 1024*1024
    int o = idx >> 10, i = idx & 1023;
    #pragma unroll
    for (int k = 0; k < 3; k++)
        Wc[(size_t)o * 3072 + k * 1024 + i] = f2b(ldin(cw, (size_t)o * 3072 + i * 3 + k, f32));
}

// ---------------- zero pad rows 0 and 1537 of xpTpad --------------------------------
__global__ void pad_zero_kernel(u16* xpT) {
    int i = blockIdx.x * 256 + threadIdx.x;   // < 8192
    xpT[i] = 0;
    xpT[(size_t)1537 * 8192 + i] = 0;
}

// ---------------- embedding gather -> bf16 xn + per-row partial sum/sumsq -----------
// NO atomics: 8192 blocks each write (s, ss) to partial[row] / partial[BL+row].
// Previous version did 16384 device-scope atomicAdds into ONE cache line -> 213 us
// of pure atomic serialization (1.5% HBM, 2% VALU). Two-stage reduction instead.
__global__ __launch_bounds__(256) void embed_kernel(const int* __restrict__ ids,
                                                    const void* __restrict__ emb,
                                                    u16* __restrict__ x,
                                                    float* __restrict__ partial,
                                                    const int* __restrict__ flagp) {
    const int f32 = flagp[0];
    const int i64 = flagp[1];
    int row = blockIdx.x;              // b*L + l
    int id = i64 ? ids[2 * row] : ids[row];
    u16* xr = x + (size_t)row * DD;
    float s = 0.f, ss = 0.f;
    for (int d = threadIdx.x; d < DD; d += 256) {
        float v = ldin(emb, (size_t)id * DD + d, f32);
        u16 t = f2b(v);
        xr[d] = t;
        v = bf2f(t);                   // round in-register; no global store->reload
        s += v; ss += v * v;
    }
    #pragma unroll
    for (int off = 32; off > 0; off >>= 1) {
        s  += __shfl_down(s,  off);
        ss += __shfl_down(ss, off);
    }
    __shared__ float smS[4], smQ[4];
    int lane = threadIdx.x & 63, wid = threadIdx.x >> 6;
    if (lane == 0) { smS[wid] = s; smQ[wid] = ss; }
    __syncthreads();
    if (threadIdx.x == 0) {
        partial[row]      = smS[0] + smS[1] + smS[2] + smS[3];
        partial[BL + row] = smQ[0] + smQ[1] + smQ[2] + smQ[3];
    }
}

// ---------------- reduce 1024 partials per sample -> mean, rsqrt(var) ---------------
__global__ __launch_bounds__(256) void finalize_stats_kernel(const float* __restrict__ partial,
                                                             float* __restrict__ stats) {
    int b = blockIdx.x;                        // 0..7
    const float* ps = partial + (size_t)b * 1024;
    const float* pq = partial + BL + (size_t)b * 1024;
    float s = 0.f, ss = 0.f;
    for (int i = threadIdx.x; i < 1024; i += 256) { s += ps[i]; ss += pq[i]; }
    #pragma unroll
    for (int off = 32; off > 0; off >>= 1) {
        s  += __shfl_down(s,  off);
        ss += __shfl_down(ss, off);
    }
    __shared__ float smS[4], smQ[4];
    int lane = threadIdx.x & 63, wid = threadIdx.x >> 6;
    if (lane == 0) { smS[wid] = s; smQ[wid] = ss; }
    __syncthreads();
    if (threadIdx.x == 0) {
        float S = smS[0] + smS[1] + smS[2] + smS[3];
        float Q = smQ[0] + smQ[1] + smQ[2] + smQ[3];
        const float inv = 1.f / (float)LD;
        float m = S * inv;
        float var = Q * inv - m * m;
        stats[16 + b] = m;
        stats[24 + b] = rsqrtf(var + 1e-5f);
    }
}

// ---------------- per-sample LN + RMSNorm (in place, bf16) ----------------
__global__ __launch_bounds__(256) void ln_rms_kernel(u16* __restrict__ x,
                                                     const void* __restrict__ rms_w,
                                                     const float* __restrict__ stats,
                                                     const int* __restrict__ flagp) {
    const int f32 = flagp[0];
    int row = blockIdx.x;
    int b = row >> 10;
    float m = stats[16 + b], rs = stats[24 + b];
    __shared__ float rowb[DD];
    __shared__ float sm[4];
    __shared__ float rmsv;
    u16* xr = x + (size_t)row * DD;
    float ss = 0.f;
    for (int d = threadIdx.x; d < DD; d += 256) {
        float t = (bf2f(xr[d]) - m) * rs;
        rowb[d] = t;
        ss += t * t;
    }
    #pragma unroll
    for (int off = 32; off > 0; off >>= 1) ss += __shfl_down(ss, off);
    int lane = threadIdx.x & 63, wid = threadIdx.x >> 6;
    if (lane == 0) sm[wid] = ss;
    __syncthreads();
    if (threadIdx.x == 0)
        rmsv = rsqrtf((sm[0] + sm[1] + sm[2] + sm[3]) * (1.f / (float)DD) + 1e-5f);
    __syncthreads();
    float rv = rmsv;
    for (int d = threadIdx.x; d < DD; d += 256)
        xr[d] = f2b(rowb[d] * rv * ldin(rms_w, d, f32));
}

// ---------------- MFMA GEMM: C[m][n] = act(sum_k A[m][k]*Bt[n][k] + bias) -----------
// A: bf16 [M][lda] row-major. Bt: bf16 [N][ldb] K-major (weights pre-transposed).
// 128x128 tile, BK=32, 256 threads (4 waves, 2x2), 4x4 mfma frags per wave.
// conv=1: Bt rows come from xpTpad with +tap row shift, col base = z*1024;
//         C offset = z*1024*ldc. BIAS_M: bias indexed by m (else by n).
// OUTMODE: 0 = bf16; 1 = dtype per flag (d_out).
template <int ACT, int BIAS_M, int OUTMODE>
__global__ __launch_bounds__(256) void mfma_gemm(const u16* __restrict__ A, int lda,
                                                 const u16* __restrict__ B, int ldb,
                                                 const void* __restrict__ bias,
                                                 void* __restrict__ Cout, int ldc,
                                                 int K, int conv,
                                                 const int* __restrict__ flagp) {
    const int f32 = flagp[0];
    const int tid = threadIdx.x;
    const int lane = tid & 63, wid = tid >> 6;
    const int wr = wid >> 1, wc = wid & 1;
    const int quad = lane >> 4, l16 = lane & 15;
    const int m0 = blockIdx.y << 7, n0 = blockIdx.x << 7;
    const size_t cbase = conv ? (size_t)blockIdx.z * 1024 * ldc : 0;
    const int colbase = conv ? (blockIdx.z << 10) : 0;

    __shared__ u16 As[128 * 32];
    __shared__ u16 Bs[128 * 32];

    f32x4 acc[4][4] = {};

    const int srow = tid >> 2;            // 0..63
    const int scol = (tid & 3) << 3;      // 0,8,16,24
    u16* ldsA0 = As + (size_t)(wid * 64) * 8;
    u16* ldsA1 = As + (size_t)(256 + wid * 64) * 8;
    u16* ldsB0 = Bs + (size_t)(wid * 64) * 8;
    u16* ldsB1 = Bs + (size_t)(256 + wid * 64) * 8;

    for (int k0 = 0; k0 < K; k0 += 32) {
        async_load16(A + (size_t)(m0 + srow) * lda + k0 + scol, ldsA0);
        async_load16(A + (size_t)(m0 + 64 + srow) * lda + k0 + scol, ldsA1);
        if (conv) {
            const int tap = k0 >> 10, ko = k0 & 1023;
            async_load16(B + (size_t)(n0 + srow + tap) * ldb + colbase + ko + scol, ldsB0);
            async_load16(B + (size_t)(n0 + 64 + srow + tap) * ldb + colbase + ko + scol, ldsB1);
        } else {
            async_load16(B + (size_t)(n0 + srow) * ldb + k0 + scol, ldsB0);
            async_load16(B + (size_t)(n0 + 64 + srow) * ldb + k0 + scol, ldsB1);
        }
        __syncthreads();
        short8 af[4], bf[4];
        #pragma unroll
        for (int mi = 0; mi < 4; mi++)
            af[mi] = *reinterpret_cast<const short8*>(As + (wr * 64 + mi * 16 + l16) * 32 + quad * 8);
        #pragma unroll
        for (int ni = 0; ni < 4; ni++)
            bf[ni] = *reinterpret_cast<const short8*>(Bs + (wc * 64 + ni * 16 + l16) * 32 + quad * 8);
        #pragma unroll
        for (int mi = 0; mi < 4; mi++)
            #pragma unroll
            for (int ni = 0; ni < 4; ni++)
                acc[mi][ni] = __builtin_amdgcn_mfma_f32_16x16x32_bf16(af[mi], bf[ni], acc[mi][ni], 0, 0, 0);
        __syncthreads();
    }

    #pragma unroll
    for (int mi = 0; mi < 4; mi++) {
        const int row = m0 + wr * 64 + mi * 16 + quad * 4;
        #pragma unroll
        for (int ni = 0; ni < 4; ni++) {
            const int col = n0 + wc * 64 + ni * 16 + l16;
            float bn = BIAS_M ? 0.f : ldin(bias, col, f32);
            #pragma unroll
            for (int r = 0; r < 4; r++) {
                float v = acc[mi][ni][r] + (BIAS_M ? ldin(bias, row + r, f32) : bn);
                if (ACT == 1) v = siluf(v);
                if (ACT == 2) v = softplusf(v);
                size_t ci = cbase + (size_t)(row + r) * ldc + col;
                if (OUTMODE == 1 && f32) ((float*)Cout)[ci] = v;
                else                     ((u16*)Cout)[ci] = f2b(v);
            }
        }
    }
}

// ---------------- Bm/Cm: BC[row, 0:16)=xco@fc2_w, [16:32)=xco@fc3_w (no bias) -------
__global__ __launch_bounds__(256) void bc_gemm_k(const u16* __restrict__ xco,
                                                 const void* __restrict__ fc2_w,
                                                 const void* __restrict__ fc3_w,
                                                 float* __restrict__ BC,
                                                 const int* __restrict__ flagp) {
    const int f32 = flagp[0];
    __shared__ float As[16][64];
    __shared__ float Ws[16][33];
    const int tid = threadIdx.x;
    const int tx = tid & 31, ty = tid >> 5;
    const int m0 = blockIdx.x << 6;
    const int arow = tid >> 2, acol = (tid & 3) << 2;
    float acc[8] = {};
    for (int k0 = 0; k0 < DD2; k0 += 16) {
        ushort4 av = *reinterpret_cast<const ushort4*>(xco + (size_t)(m0 + arow) * DD2 + k0 + acol);
        As[acol + 0][arow] = bf2f(av.x);
        As[acol + 1][arow] = bf2f(av.y);
        As[acol + 2][arow] = bf2f(av.z);
        As[acol + 3][arow] = bf2f(av.w);
        int idx = tid << 1;
        int r = idx >> 5;
        #pragma unroll
        for (int e = 0; e < 2; e++) {
            int n = (idx & 31) + e;
            float v = (n < 16) ? ldin(fc2_w, (size_t)(k0 + r) * 16 + n, f32)
                               : ldin(fc3_w, (size_t)(k0 + r) * 16 + (n - 16), f32);
            Ws[r][n] = v;
        }
        __syncthreads();
        #pragma unroll
        for (int kk = 0; kk < 16; kk++) {
            float w = Ws[kk][tx];
            #pragma unroll
            for (int i = 0; i < 8; i++) acc[i] += As[kk][ty * 8 + i] * w;
        }
        __syncthreads();
    }
    #pragma unroll
    for (int i = 0; i < 8; i++)
        BC[(size_t)(m0 + ty * 8 + i) * 32 + tx] = acc[i];
}

// ---------------- s[row] = sum_n (Bm+b2)[n] * (Cm+b3)[n] ----------------
__global__ void s_kernel(const float* __restrict__ BC,
                         const void* __restrict__ fc2_b,
                         const void* __restrict__ fc3_b,
                         float* __restrict__ s,
                         const int* __restrict__ flagp) {
    const int f32 = flagp[0];
    int row = blockIdx.x * 256 + threadIdx.x;
    if (row >= BL) return;
    const float* p = BC + (size_t)row * 32;
    float acc = 0.f;
    #pragma unroll
    for (int n = 0; n < 16; n++) {
        float Bn = p[n] + ldin(fc2_b, n, f32);
        float Cn = p[16 + n] + ldin(fc3_b, n, f32);
        acc += Bn * Cn;
    }
    s[row] = acc;
}

// ---------------- z = silu(xco*delta*s) * xres   (in place over xco) -------------
__global__ void z_kernel(u16* __restrict__ xco_z,
                         const u16* __restrict__ delta,
                         const float* __restrict__ s,
                         const u16* __restrict__ xres) {
    unsigned int idx = blockIdx.x * 256u + threadIdx.x;   // < 12582912
    int row = idx / DD2;
    float y = bf2f(xco_z[idx]) * bf2f(delta[idx]) * s[row];
    xco_z[idx] = f2b(siluf(y) * bf2f(xres[idx]));
}

// ---------------- pooled = max over seq of out (dtype per flag) ----------------
__global__ void pool_kernel(void* __restrict__ outp, const int* __restrict__ flagp) {
    const int f32 = flagp[0];
    int idx = blockIdx.x * 256 + threadIdx.x;  // < 6144
    if (idx >= BB * DD) return;
    int b = idx / DD, d = idx % DD;
    float m = -3.4e38f;
    if (f32) {
        const float* p = (const float*)outp + (size_t)b * LD + d;
        for (int l = 0; l < LL; l++) m = fmaxf(m, p[(size_t)l * DD]);
        ((float*)outp)[(size_t)BL * DD + idx] = m;
    } else {
        const u16* p = (const u16*)outp + (size_t)b * LD + d;
        for (int l = 0; l < LL; l++) m = fmaxf(m, bf2f(p[(size_t)l * DD]));
        ((u16*)outp)[(size_t)BL * DD + idx] = f2b(m);
    }
}

extern "C" void kernel_launch(void* const* d_in, const int* in_sizes, int n_in,
                              void* d_out, int out_size, void* d_ws, size_t ws_size,
                              hipStream_t stream) {
    const int*  ids    = (const int*)d_in[0];
    const void* emb    = d_in[1];
    const void* rms_w  = d_in[2];
    const void* W_in   = d_in[3];
    const void* b_in   = d_in[4];
    const void* conv_w = d_in[5];
    const void* conv_b = d_in[6];
    const void* W_cl   = d_in[7];
    const void* b_cl   = d_in[8];
    const void* fc1_w  = d_in[9];
    const void* fc1_b  = d_in[10];
    const void* fc2_w  = d_in[11];
    const void* fc2_b  = d_in[12];
    const void* fc3_w  = d_in[13];
    const void* fc3_b  = d_in[14];
    // d_in[15] = A : unused (zero initial state kills exp(delta@A) term)
    const void* W_D    = d_in[16];
    const void* b_D    = d_in[17];
    const void* W_out  = d_in[18];
    const void* b_out  = d_in[19];

    char* ws = (char*)d_ws;
    u16*   Wt_in  = (u16*)(ws);                  // [1536][768]   2,359,296
    u16*   Wt_cl  = (u16*)(ws + 2359296);        // [1536][1536]  4,718,592
    u16*   Wt_fc1 = (u16*)(ws + 7077888);        // [1536][1536]  4,718,592
    u16*   Wt_D   = (u16*)(ws + 11796480);       // [1536][768]   2,359,296
    u16*   Wt_out = (u16*)(ws + 14155776);       // [768][1536]   2,359,296
    u16*   Wc     = (u16*)(ws + 16515072);       // [1024][3072]  6,291,456
    u16*   xpT    = (u16*)(ws + 22806528);       // [1538][8192]  25,198,592 (later: delta)
    u16*   xca    = (u16*)(ws + 48005120);       // [8192][1536]  25,165,824 (later: xres)
    u16*   xco    = (u16*)(ws + 73170944);       // [8192][1536]  25,165,824 (z in place)
    float* sbuf   = (float*)(ws + 98336768);     // 32,768
    float* stats  = (float*)(ws + 98369536);     // 128
    int*   flag   = (int*)(ws + 98369664);       // 128
    float* BC     = (float*)(ws + 98369792);     // 1,048,576 (early: stats partials 64KB)
    const size_t NEED = 99418368;

    if (ws_size < NEED) {
        float v = 10000.f + (float)(ws_size >> 20);
        diag_kernel<<<(out_size + 255) / 256, 256, 0, stream>>>((u16*)d_out, out_size, v);
        return;
    }

    u16* xn    = (u16*)d_out;         // bf16 staging, dead before final GEMM
    u16* delta = xpT;                 // reuse after conv
    u16* xres  = xca;                 // reuse after xco GEMM

    detect_kernel<<<1, 256, 0, stream>>>(emb, ids, flag, stats);
    // weight conversions (bf16, transposed to [N][K])
    wt_convert<<<dim3(1536 / 32, 768 / 32), 256, 0, stream>>>(W_in,  Wt_in,  768,  1536, flag);
    wt_convert<<<dim3(1536 / 32, 1536 / 32), 256, 0, stream>>>(W_cl,  Wt_cl,  1536, 1536, flag);
    wt_convert<<<dim3(1536 / 32, 1536 / 32), 256, 0, stream>>>(fc1_w, Wt_fc1, 1536, 1536, flag);
    wt_convert<<<dim3(1536 / 32, 768 / 32), 256, 0, stream>>>(W_D,   Wt_D,   768,  1536, flag);
    wt_convert<<<dim3(768 / 32, 1536 / 32), 256, 0, stream>>>(W_out, Wt_out, 1536, 768,  flag);
    convw_convert<<<4096, 256, 0, stream>>>(conv_w, Wc, flag);
    pad_zero_kernel<<<32, 256, 0, stream>>>(xpT);

    // embed: per-row partials into BC scratch (dead until bc_gemm), then 8-block reduce
    embed_kernel<<<BL, 256, 0, stream>>>(ids, emb, xn, BC, flag);
    finalize_stats_kernel<<<8, 256, 0, stream>>>(BC, stats);
    ln_rms_kernel<<<BL, 256, 0, stream>>>(xn, rms_w, stats, flag);

    // xpT[f+1][(b,i)] = (xn @ W_in + b_in)^T : A=Wt_in (m=f), B=xn (n=(b,i))
    mfma_gemm<0, 1, 0><<<dim3(64, 12, 1), 256, 0, stream>>>(
        Wt_in, 768, xn, 768, b_in, xpT + 8192, 8192, 768, 0, flag);
    // xca[b][o][f] = silu(conv(xp) + conv_b) : A=Wc (m=o, K=3*1024), B=xpT tap-shifted
    mfma_gemm<1, 1, 0><<<dim3(12, 8, 8), 256, 0, stream>>>(
        Wc, 3072, xpT, 8192, conv_b, xca, 1536, 3072, 1, flag);
    // xco = xca @ W_cl + b_cl
    mfma_gemm<0, 0, 0><<<dim3(12, 64, 1), 256, 0, stream>>>(
        xca, 1536, Wt_cl, 1536, b_cl, xco, 1536, 1536, 0, flag);
    // delta = softplus(xco @ fc1_w + fc1_b)  (into xpT slot)
    mfma_gemm<2, 0, 0><<<dim3(12, 64, 1), 256, 0, stream>>>(
        xco, 1536, Wt_fc1, 1536, fc1_b, delta, 1536, 1536, 0, flag);
    // BC = xco @ [fc2_w | fc3_w]; s = rowwise dot
    bc_gemm_k<<<BL / 64, 256, 0, stream>>>(xco, fc2_w, fc3_w, BC, flag);
    s_kernel<<<BL / 256, 256, 0, stream>>>(BC, fc2_b, fc3_b, sbuf, flag);
    // xres = silu(xn @ W_D + b_D)  (into xca slot)
    mfma_gemm<1, 0, 0><<<dim3(12, 64, 1), 256, 0, stream>>>(
        xn, 768, Wt_D, 768, b_D, xres, 1536, 768, 0, flag);
    // z = silu(xco * delta * s) * xres  (in place over xco)
    z_kernel<<<(BL * DD2) / 256, 256, 0, stream>>>(xco, delta, sbuf, xres);
    // out = z @ W_out + b_out -> d_out (overwrites xn staging, dead)
    mfma_gemm<0, 0, 1><<<dim3(6, 64, 1), 256, 0, stream>>>(
        xco, 1536, Wt_out, 1536, b_out, d_out, 768, 1536, 0, flag);
    // pooled = max over seq
    pool_kernel<<<(BB * DD + 255) / 256, 256, 0, stream>>>(d_out, flag);
}

// Round 3
// 855.622 us; speedup vs baseline: 1.4108x; 1.1806x over previous
//
#include <hip/hip_runtime.h>
#include <hip/hip_bf16.h>

typedef unsigned short u16;
typedef __attribute__((ext_vector_type(8))) short short8;
typedef __attribute__((ext_vector_type(4))) float f32x4;

#define BB 8
#define LL 1024
#define DD 768
#define DD2 1536
#define BL 8192           // B*L
#define LD 786432         // L*D elements per sample
#define PCH 32            // pool chunks per sample
#define PROWS (LL / PCH)  // rows per pool chunk

__device__ __forceinline__ float bf2f(u16 u) {
    return __uint_as_float(((unsigned int)u) << 16);
}
__device__ __forceinline__ u16 f2b(float f) {
    __hip_bfloat16 h = __float2bfloat16(f);
    return *reinterpret_cast<u16*>(&h);
}
// dual-dtype input load: f32 ? fp32 array : bf16 array
__device__ __forceinline__ float ldin(const void* p, size_t i, int f32) {
    return f32 ? ((const float*)p)[i] : bf2f(((const u16*)p)[i]);
}
__device__ __forceinline__ float siluf(float x) { return x / (1.f + expf(-x)); }
__device__ __forceinline__ float softplusf(float x) { return (x > 20.f) ? x : log1pf(expf(x)); }

// async global->LDS, 16B per lane; LDS dest = wave-uniform base + lane*16
__device__ __forceinline__ void async_load16(const u16* g, u16* l) {
    __builtin_amdgcn_global_load_lds(
        (const __attribute__((address_space(1))) unsigned int*)g,
        (__attribute__((address_space(3))) unsigned int*)l, 16, 0, 0);
}

// ---------------- dtype detect (float width on emb, int width on ids) --------------
__global__ void detect_kernel(const void* emb, const int* ids, int* flag, float* stats) {
    __shared__ int cnt, nz;
    if (threadIdx.x == 0) { cnt = 0; nz = 0; }
    __syncthreads();
    const u16* p = (const u16*)emb;
    int lc = 0, ln = 0;
    for (int k = threadIdx.x; k < 4096; k += 256) {
        int e = (p[2 * k] >> 7) & 0xFF;
        if (e >= 90 && e <= 130) lc++;
        if (ids[2 * k + 1] != 0) ln++;
    }
    atomicAdd(&cnt, lc);
    atomicAdd(&nz, ln);
    __syncthreads();
    if (threadIdx.x == 0) {
        flag[0] = (cnt < 2048) ? 1 : 0;   // 1 = floats are fp32
        flag[1] = (nz < 8) ? 1 : 0;       // 1 = ids are int64
    }
    if (threadIdx.x < 16) stats[threadIdx.x] = 0.f;
}

// ---------------- diagnostic fill (ws too small): error print reveals ws MB ---------
__global__ void diag_kernel(u16* out, int n, float val) {
    int i = blockIdx.x * 256 + threadIdx.x;
    if (i < n) out[i] = f2b(val);
}

// ---------------- weight convert: Wt[n][k] = (bf16) W[k][n] -------------------------
__global__ __launch_bounds__(256) void wt_convert(const void* __restrict__ W,
                                                  u16* __restrict__ Wt,
                                                  int K, int N,
                                                  const int* __restrict__ flagp) {
    const int f32 = flagp[0];
    __shared__ float t[32][33];
    int n0 = blockIdx.x * 32, k0 = blockIdx.y * 32;
    int c = threadIdx.x & 31, r4 = threadIdx.x >> 5;
    #pragma unroll
    for (int rr = 0; rr < 4; rr++) {
        int r = r4 * 4 + rr;
        t[r][c] = ldin(W, (size_t)(k0 + r) * N + n0 + c, f32);
    }
    __syncthreads();
    #pragma unroll
    for (int rr = 0; rr < 4; rr++) {
        int r = r4 * 4 + rr;
        Wt[(size_t)(n0 + r) * K + k0 + c] = f2b(t[c][r]);
    }
}

// ---------------- conv weight: Wc[o][k*1024+i] = (bf16) conv_w[o][i][k] -------------
__global__ __launch_bounds__(256) void convw_convert(const void* __restrict__ cw,
                                                     u16* __restrict__ Wc,
                                                     const int* __restrict__ flagp) {
    const int f32 = flagp[0];
    size_t idx = (size_t)blockIdx.x * 256 + threadIdx.x;   // < 1024*1024
    int o = idx >> 10, i = idx & 1023;
    #pragma unroll
    for (int k = 0; k < 3; k++)
        Wc[(size_t)o * 3072 + k * 1024 + i] = f2b(ldin(cw, (size_t)o * 3072 + i * 3 + k, f32));
}

// ---------------- zero pad rows 0 and 1537 of xpTpad --------------------------------
__global__ void pad_zero_kernel(u16* xpT) {
    int i = blockIdx.x * 256 + threadIdx.x;   // < 8192
    xpT[i] = 0;
    xpT[(size_t)1537 * 8192 + i] = 0;
}

// ---------------- embedding gather -> bf16 xn + per-row partial sum/sumsq -----------
// NO atomics: 8192 blocks each write (s, ss) to partial[row] / partial[BL+row].
__global__ __launch_bounds__(256) void embed_kernel(const int* __restrict__ ids,
                                                    const void* __restrict__ emb,
                                                    u16* __restrict__ x,
                                                    float* __restrict__ partial,
                                                    const int* __restrict__ flagp) {
    const int f32 = flagp[0];
    const int i64 = flagp[1];
    int row = blockIdx.x;              // b*L + l
    int id = i64 ? ids[2 * row] : ids[row];
    u16* xr = x + (size_t)row * DD;
    float s = 0.f, ss = 0.f;
    for (int d = threadIdx.x; d < DD; d += 256) {
        float v = ldin(emb, (size_t)id * DD + d, f32);
        u16 t = f2b(v);
        xr[d] = t;
        v = bf2f(t);                   // round in-register; no global store->reload
        s += v; ss += v * v;
    }
    #pragma unroll
    for (int off = 32; off > 0; off >>= 1) {
        s  += __shfl_down(s,  off);
        ss += __shfl_down(ss, off);
    }
    __shared__ float smS[4], smQ[4];
    int lane = threadIdx.x & 63, wid = threadIdx.x >> 6;
    if (lane == 0) { smS[wid] = s; smQ[wid] = ss; }
    __syncthreads();
    if (threadIdx.x == 0) {
        partial[row]      = smS[0] + smS[1] + smS[2] + smS[3];
        partial[BL + row] = smQ[0] + smQ[1] + smQ[2] + smQ[3];
    }
}

// ---------------- reduce 1024 partials per sample -> mean, rsqrt(var) ---------------
__global__ __launch_bounds__(256) void finalize_stats_kernel(const float* __restrict__ partial,
                                                             float* __restrict__ stats) {
    int b = blockIdx.x;                        // 0..7
    const float* ps = partial + (size_t)b * 1024;
    const float* pq = partial + BL + (size_t)b * 1024;
    float s = 0.f, ss = 0.f;
    for (int i = threadIdx.x; i < 1024; i += 256) { s += ps[i]; ss += pq[i]; }
    #pragma unroll
    for (int off = 32; off > 0; off >>= 1) {
        s  += __shfl_down(s,  off);
        ss += __shfl_down(ss, off);
    }
    __shared__ float smS[4], smQ[4];
    int lane = threadIdx.x & 63, wid = threadIdx.x >> 6;
    if (lane == 0) { smS[wid] = s; smQ[wid] = ss; }
    __syncthreads();
    if (threadIdx.x == 0) {
        float S = smS[0] + smS[1] + smS[2] + smS[3];
        float Q = smQ[0] + smQ[1] + smQ[2] + smQ[3];
        const float inv = 1.f / (float)LD;
        float m = S * inv;
        float var = Q * inv - m * m;
        stats[16 + b] = m;
        stats[24 + b] = rsqrtf(var + 1e-5f);
    }
}

// ---------------- per-sample LN + RMSNorm (in place, bf16) ----------------
__global__ __launch_bounds__(256) void ln_rms_kernel(u16* __restrict__ x,
                                                     const void* __restrict__ rms_w,
                                                     const float* __restrict__ stats,
                                                     const int* __restrict__ flagp) {
    const int f32 = flagp[0];
    int row = blockIdx.x;
    int b = row >> 10;
    float m = stats[16 + b], rs = stats[24 + b];
    __shared__ float rowb[DD];
    __shared__ float sm[4];
    __shared__ float rmsv;
    u16* xr = x + (size_t)row * DD;
    float ss = 0.f;
    for (int d = threadIdx.x; d < DD; d += 256) {
        float t = (bf2f(xr[d]) - m) * rs;
        rowb[d] = t;
        ss += t * t;
    }
    #pragma unroll
    for (int off = 32; off > 0; off >>= 1) ss += __shfl_down(ss, off);
    int lane = threadIdx.x & 63, wid = threadIdx.x >> 6;
    if (lane == 0) sm[wid] = ss;
    __syncthreads();
    if (threadIdx.x == 0)
        rmsv = rsqrtf((sm[0] + sm[1] + sm[2] + sm[3]) * (1.f / (float)DD) + 1e-5f);
    __syncthreads();
    float rv = rmsv;
    for (int d = threadIdx.x; d < DD; d += 256)
        xr[d] = f2b(rowb[d] * rv * ldin(rms_w, d, f32));
}

// ---------------- MFMA GEMM: C[m][n] = act(sum_k A[m][k]*Bt[n][k] + bias) -----------
// A: bf16 [M][lda] row-major. Bt: bf16 [N][ldb] K-major (weights pre-transposed).
// 128x128 tile, BK=32, 256 threads (4 waves, 2x2), 4x4 mfma frags per wave.
// conv=1: Bt rows come from xpTpad with +tap row shift, col base = z*1024;
//         C offset = z*1024*ldc. BIAS_M: bias indexed by m (else by n).
// OUTMODE: 0 = bf16; 1 = dtype per flag (d_out).
template <int ACT, int BIAS_M, int OUTMODE>
__global__ __launch_bounds__(256) void mfma_gemm(const u16* __restrict__ A, int lda,
                                                 const u16* __restrict__ B, int ldb,
                                                 const void* __restrict__ bias,
                                                 void* __restrict__ Cout, int ldc,
                                                 int K, int conv,
                                                 const int* __restrict__ flagp) {
    const int f32 = flagp[0];
    const int tid = threadIdx.x;
    const int lane = tid & 63, wid = tid >> 6;
    const int wr = wid >> 1, wc = wid & 1;
    const int quad = lane >> 4, l16 = lane & 15;
    const int m0 = blockIdx.y << 7, n0 = blockIdx.x << 7;
    const size_t cbase = conv ? (size_t)blockIdx.z * 1024 * ldc : 0;
    const int colbase = conv ? (blockIdx.z << 10) : 0;

    __shared__ u16 As[128 * 32];
    __shared__ u16 Bs[128 * 32];

    f32x4 acc[4][4] = {};

    const int srow = tid >> 2;            // 0..63
    const int scol = (tid & 3) << 3;      // 0,8,16,24
    u16* ldsA0 = As + (size_t)(wid * 64) * 8;
    u16* ldsA1 = As + (size_t)(256 + wid * 64) * 8;
    u16* ldsB0 = Bs + (size_t)(wid * 64) * 8;
    u16* ldsB1 = Bs + (size_t)(256 + wid * 64) * 8;

    for (int k0 = 0; k0 < K; k0 += 32) {
        async_load16(A + (size_t)(m0 + srow) * lda + k0 + scol, ldsA0);
        async_load16(A + (size_t)(m0 + 64 + srow) * lda + k0 + scol, ldsA1);
        if (conv) {
            const int tap = k0 >> 10, ko = k0 & 1023;
            async_load16(B + (size_t)(n0 + srow + tap) * ldb + colbase + ko + scol, ldsB0);
            async_load16(B + (size_t)(n0 + 64 + srow + tap) * ldb + colbase + ko + scol, ldsB1);
        } else {
            async_load16(B + (size_t)(n0 + srow) * ldb + k0 + scol, ldsB0);
            async_load16(B + (size_t)(n0 + 64 + srow) * ldb + k0 + scol, ldsB1);
        }
        __syncthreads();
        short8 af[4], bf[4];
        #pragma unroll
        for (int mi = 0; mi < 4; mi++)
            af[mi] = *reinterpret_cast<const short8*>(As + (wr * 64 + mi * 16 + l16) * 32 + quad * 8);
        #pragma unroll
        for (int ni = 0; ni < 4; ni++)
            bf[ni] = *reinterpret_cast<const short8*>(Bs + (wc * 64 + ni * 16 + l16) * 32 + quad * 8);
        #pragma unroll
        for (int mi = 0; mi < 4; mi++)
            #pragma unroll
            for (int ni = 0; ni < 4; ni++)
                acc[mi][ni] = __builtin_amdgcn_mfma_f32_16x16x32_bf16(af[mi], bf[ni], acc[mi][ni], 0, 0, 0);
        __syncthreads();
    }

    #pragma unroll
    for (int mi = 0; mi < 4; mi++) {
        const int row = m0 + wr * 64 + mi * 16 + quad * 4;
        #pragma unroll
        for (int ni = 0; ni < 4; ni++) {
            const int col = n0 + wc * 64 + ni * 16 + l16;
            float bn = BIAS_M ? 0.f : ldin(bias, col, f32);
            #pragma unroll
            for (int r = 0; r < 4; r++) {
                float v = acc[mi][ni][r] + (BIAS_M ? ldin(bias, row + r, f32) : bn);
                if (ACT == 1) v = siluf(v);
                if (ACT == 2) v = softplusf(v);
                size_t ci = cbase + (size_t)(row + r) * ldc + col;
                if (OUTMODE == 1 && f32) ((float*)Cout)[ci] = v;
                else                     ((u16*)Cout)[ci] = f2b(v);
            }
        }
    }
}

// ---------------- Bm/Cm: BC[row, 0:16)=xco@fc2_w, [16:32)=xco@fc3_w (no bias) -------
__global__ __launch_bounds__(256) void bc_gemm_k(const u16* __restrict__ xco,
                                                 const void* __restrict__ fc2_w,
                                                 const void* __restrict__ fc3_w,
                                                 float* __restrict__ BC,
                                                 const int* __restrict__ flagp) {
    const int f32 = flagp[0];
    __shared__ float As[16][64];
    __shared__ float Ws[16][33];
    const int tid = threadIdx.x;
    const int tx = tid & 31, ty = tid >> 5;
    const int m0 = blockIdx.x << 6;
    const int arow = tid >> 2, acol = (tid & 3) << 2;
    float acc[8] = {};
    for (int k0 = 0; k0 < DD2; k0 += 16) {
        ushort4 av = *reinterpret_cast<const ushort4*>(xco + (size_t)(m0 + arow) * DD2 + k0 + acol);
        As[acol + 0][arow] = bf2f(av.x);
        As[acol + 1][arow] = bf2f(av.y);
        As[acol + 2][arow] = bf2f(av.z);
        As[acol + 3][arow] = bf2f(av.w);
        int idx = tid << 1;
        int r = idx >> 5;
        #pragma unroll
        for (int e = 0; e < 2; e++) {
            int n = (idx & 31) + e;
            float v = (n < 16) ? ldin(fc2_w, (size_t)(k0 + r) * 16 + n, f32)
                               : ldin(fc3_w, (size_t)(k0 + r) * 16 + (n - 16), f32);
            Ws[r][n] = v;
        }
        __syncthreads();
        #pragma unroll
        for (int kk = 0; kk < 16; kk++) {
            float w = Ws[kk][tx];
            #pragma unroll
            for (int i = 0; i < 8; i++) acc[i] += As[kk][ty * 8 + i] * w;
        }
        __syncthreads();
    }
    #pragma unroll
    for (int i = 0; i < 8; i++)
        BC[(size_t)(m0 + ty * 8 + i) * 32 + tx] = acc[i];
}

// ---------------- s[row] = sum_n (Bm+b2)[n] * (Cm+b3)[n] ----------------
__global__ void s_kernel(const float* __restrict__ BC,
                         const void* __restrict__ fc2_b,
                         const void* __restrict__ fc3_b,
                         float* __restrict__ s,
                         const int* __restrict__ flagp) {
    const int f32 = flagp[0];
    int row = blockIdx.x * 256 + threadIdx.x;
    if (row >= BL) return;
    const float* p = BC + (size_t)row * 32;
    float acc = 0.f;
    #pragma unroll
    for (int n = 0; n < 16; n++) {
        float Bn = p[n] + ldin(fc2_b, n, f32);
        float Cn = p[16 + n] + ldin(fc3_b, n, f32);
        acc += Bn * Cn;
    }
    s[row] = acc;
}

// ---------------- z = silu(xco*delta*s) * xres   (in place over xco) -------------
__global__ void z_kernel(u16* __restrict__ xco_z,
                         const u16* __restrict__ delta,
                         const float* __restrict__ s,
                         const u16* __restrict__ xres) {
    unsigned int idx = blockIdx.x * 256u + threadIdx.x;   // < 12582912
    int row = idx / DD2;
    float y = bf2f(xco_z[idx]) * bf2f(delta[idx]) * s[row];
    xco_z[idx] = f2b(siluf(y) * bf2f(xres[idx]));
}

// ---------------- pool stage 1: per-(chunk,sample) max over PROWS rows --------------
// Old pool_kernel: 24 blocks, 1% occupancy, serial 1024-deep dependent fmax chain
// over 3KB-strided rows -> 170 us at 0.9% HBM (latency-bound). Now: 256 blocks,
// coalesced row reads, 32-deep chains, partials into BC scratch (dead by now).
__global__ __launch_bounds__(256) void pool1_kernel(const void* __restrict__ outp,
                                                    float* __restrict__ partial,
                                                    const int* __restrict__ flagp) {
    const int f32 = flagp[0];
    const int ch = blockIdx.x, b = blockIdx.y;
    const int l0 = ch * PROWS;
    const int t = threadIdx.x;
    float m0 = -3.4e38f, m1 = -3.4e38f, m2 = -3.4e38f;
    if (f32) {
        const float* base = (const float*)outp + (size_t)b * LD + (size_t)l0 * DD;
        for (int l = 0; l < PROWS; l++) {
            const float* row = base + (size_t)l * DD;
            m0 = fmaxf(m0, row[t]);
            m1 = fmaxf(m1, row[t + 256]);
            m2 = fmaxf(m2, row[t + 512]);
        }
    } else {
        const u16* base = (const u16*)outp + (size_t)b * LD + (size_t)l0 * DD;
        for (int l = 0; l < PROWS; l++) {
            const u16* row = base + (size_t)l * DD;
            m0 = fmaxf(m0, bf2f(row[t]));
            m1 = fmaxf(m1, bf2f(row[t + 256]));
            m2 = fmaxf(m2, bf2f(row[t + 512]));
        }
    }
    float* pp = partial + (size_t)ch * (BB * DD) + (size_t)b * DD;
    pp[t]       = m0;
    pp[t + 256] = m1;
    pp[t + 512] = m2;
}

// ---------------- pool stage 2: reduce PCH partials -> pooled row -------------------
__global__ void pool2_kernel(void* __restrict__ outp, const float* __restrict__ partial,
                             const int* __restrict__ flagp) {
    const int f32 = flagp[0];
    int idx = blockIdx.x * 256 + threadIdx.x;  // < 6144
    if (idx >= BB * DD) return;
    float m = -3.4e38f;
    #pragma unroll
    for (int ch = 0; ch < PCH; ch++)
        m = fmaxf(m, partial[(size_t)ch * (BB * DD) + idx]);
    if (f32) ((float*)outp)[(size_t)BL * DD + idx] = m;
    else     ((u16*)outp)[(size_t)BL * DD + idx] = f2b(m);
}

extern "C" void kernel_launch(void* const* d_in, const int* in_sizes, int n_in,
                              void* d_out, int out_size, void* d_ws, size_t ws_size,
                              hipStream_t stream) {
    const int*  ids    = (const int*)d_in[0];
    const void* emb    = d_in[1];
    const void* rms_w  = d_in[2];
    const void* W_in   = d_in[3];
    const void* b_in   = d_in[4];
    const void* conv_w = d_in[5];
    const void* conv_b = d_in[6];
    const void* W_cl   = d_in[7];
    const void* b_cl   = d_in[8];
    const void* fc1_w  = d_in[9];
    const void* fc1_b  = d_in[10];
    const void* fc2_w  = d_in[11];
    const void* fc2_b  = d_in[12];
    const void* fc3_w  = d_in[13];
    const void* fc3_b  = d_in[14];
    // d_in[15] = A : unused (zero initial state kills exp(delta@A) term)
    const void* W_D    = d_in[16];
    const void* b_D    = d_in[17];
    const void* W_out  = d_in[18];
    const void* b_out  = d_in[19];

    char* ws = (char*)d_ws;
    u16*   Wt_in  = (u16*)(ws);                  // [1536][768]   2,359,296
    u16*   Wt_cl  = (u16*)(ws + 2359296);        // [1536][1536]  4,718,592
    u16*   Wt_fc1 = (u16*)(ws + 7077888);        // [1536][1536]  4,718,592
    u16*   Wt_D   = (u16*)(ws + 11796480);       // [1536][768]   2,359,296
    u16*   Wt_out = (u16*)(ws + 14155776);       // [768][1536]   2,359,296
    u16*   Wc     = (u16*)(ws + 16515072);       // [1024][3072]  6,291,456
    u16*   xpT    = (u16*)(ws + 22806528);       // [1538][8192]  25,198,592 (later: delta)
    u16*   xca    = (u16*)(ws + 48005120);       // [8192][1536]  25,165,824 (later: xres)
    u16*   xco    = (u16*)(ws + 73170944);       // [8192][1536]  25,165,824 (z in place)
    float* sbuf   = (float*)(ws + 98336768);     // 32,768
    float* stats  = (float*)(ws + 98369536);     // 128
    int*   flag   = (int*)(ws + 98369664);       // 128
    float* BC     = (float*)(ws + 98369792);     // 1,048,576 (early: stats partials; late: pool partials)
    const size_t NEED = 99418368;

    if (ws_size < NEED) {
        float v = 10000.f + (float)(ws_size >> 20);
        diag_kernel<<<(out_size + 255) / 256, 256, 0, stream>>>((u16*)d_out, out_size, v);
        return;
    }

    u16* xn    = (u16*)d_out;         // bf16 staging, dead before final GEMM
    u16* delta = xpT;                 // reuse after conv
    u16* xres  = xca;                 // reuse after xco GEMM

    detect_kernel<<<1, 256, 0, stream>>>(emb, ids, flag, stats);
    // weight conversions (bf16, transposed to [N][K])
    wt_convert<<<dim3(1536 / 32, 768 / 32), 256, 0, stream>>>(W_in,  Wt_in,  768,  1536, flag);
    wt_convert<<<dim3(1536 / 32, 1536 / 32), 256, 0, stream>>>(W_cl,  Wt_cl,  1536, 1536, flag);
    wt_convert<<<dim3(1536 / 32, 1536 / 32), 256, 0, stream>>>(fc1_w, Wt_fc1, 1536, 1536, flag);
    wt_convert<<<dim3(1536 / 32, 768 / 32), 256, 0, stream>>>(W_D,   Wt_D,   768,  1536, flag);
    wt_convert<<<dim3(768 / 32, 1536 / 32), 256, 0, stream>>>(W_out, Wt_out, 1536, 768,  flag);
    convw_convert<<<4096, 256, 0, stream>>>(conv_w, Wc, flag);
    pad_zero_kernel<<<32, 256, 0, stream>>>(xpT);

    // embed: per-row partials into BC scratch (dead until bc_gemm), then 8-block reduce
    embed_kernel<<<BL, 256, 0, stream>>>(ids, emb, xn, BC, flag);
    finalize_stats_kernel<<<8, 256, 0, stream>>>(BC, stats);
    ln_rms_kernel<<<BL, 256, 0, stream>>>(xn, rms_w, stats, flag);

    // xpT[f+1][(b,i)] = (xn @ W_in + b_in)^T : A=Wt_in (m=f), B=xn (n=(b,i))
    mfma_gemm<0, 1, 0><<<dim3(64, 12, 1), 256, 0, stream>>>(
        Wt_in, 768, xn, 768, b_in, xpT + 8192, 8192, 768, 0, flag);
    // xca[b][o][f] = silu(conv(xp) + conv_b) : A=Wc (m=o, K=3*1024), B=xpT tap-shifted
    mfma_gemm<1, 1, 0><<<dim3(12, 8, 8), 256, 0, stream>>>(
        Wc, 3072, xpT, 8192, conv_b, xca, 1536, 3072, 1, flag);
    // xco = xca @ W_cl + b_cl
    mfma_gemm<0, 0, 0><<<dim3(12, 64, 1), 256, 0, stream>>>(
        xca, 1536, Wt_cl, 1536, b_cl, xco, 1536, 1536, 0, flag);
    // delta = softplus(xco @ fc1_w + fc1_b)  (into xpT slot)
    mfma_gemm<2, 0, 0><<<dim3(12, 64, 1), 256, 0, stream>>>(
        xco, 1536, Wt_fc1, 1536, fc1_b, delta, 1536, 1536, 0, flag);
    // BC = xco @ [fc2_w | fc3_w]; s = rowwise dot
    bc_gemm_k<<<BL / 64, 256, 0, stream>>>(xco, fc2_w, fc3_w, BC, flag);
    s_kernel<<<BL / 256, 256, 0, stream>>>(BC, fc2_b, fc3_b, sbuf, flag);
    // xres = silu(xn @ W_D + b_D)  (into xca slot)
    mfma_gemm<1, 0, 0><<<dim3(12, 64, 1), 256, 0, stream>>>(
        xn, 768, Wt_D, 768, b_D, xres, 1536, 768, 0, flag);
    // z = silu(xco * delta * s) * xres  (in place over xco)
    z_kernel<<<(BL * DD2) / 256, 256, 0, stream>>>(xco, delta, sbuf, xres);
    // out = z @ W_out + b_out -> d_out (overwrites xn staging, dead)
    mfma_gemm<0, 0, 1><<<dim3(6, 64, 1), 256, 0, stream>>>(
        xco, 1536, Wt_out, 1536, b_out, d_out, 768, 1536, 0, flag);
    // pooled = max over seq: two-stage, BC scratch (dead after s_kernel)
    pool1_kernel<<<dim3(PCH, BB), 256, 0, stream>>>(d_out, BC, flag);
    pool2_kernel<<<(BB * DD + 255) / 256, 256, 0, stream>>>(d_out, BC, flag);
}

// Round 4
// 719.409 us; speedup vs baseline: 1.6779x; 1.1893x over previous
//
#include <hip/hip_runtime.h>
#include <hip/hip_bf16.h>

typedef unsigned short u16;
typedef __attribute__((ext_vector_type(8))) short short8;
typedef __attribute__((ext_vector_type(4))) float f32x4;

#define BB 8
#define LL 1024
#define DD 768
#define DD2 1536
#define BL 8192           // B*L
#define LD 786432         // L*D elements per sample
#define PCH 32            // pool chunks per sample
#define PROWS (LL / PCH)  // rows per pool chunk

__device__ __forceinline__ float bf2f(u16 u) {
    return __uint_as_float(((unsigned int)u) << 16);
}
__device__ __forceinline__ u16 f2b(float f) {
    __hip_bfloat16 h = __float2bfloat16(f);
    return *reinterpret_cast<u16*>(&h);
}
// dual-dtype input load: f32 ? fp32 array : bf16 array
__device__ __forceinline__ float ldin(const void* p, size_t i, int f32) {
    return f32 ? ((const float*)p)[i] : bf2f(((const u16*)p)[i]);
}
__device__ __forceinline__ float siluf(float x) { return x / (1.f + expf(-x)); }
__device__ __forceinline__ float softplusf(float x) { return (x > 20.f) ? x : log1pf(expf(x)); }

// async global->LDS, 16B per lane; LDS dest = wave-uniform base + lane*16
__device__ __forceinline__ void async_load16(const u16* g, u16* l) {
    __builtin_amdgcn_global_load_lds(
        (const __attribute__((address_space(1))) unsigned int*)g,
        (__attribute__((address_space(3))) unsigned int*)l, 16, 0, 0);
}

// ---------------- dtype detect (float width on emb, int width on ids) --------------
__global__ void detect_kernel(const void* emb, const int* ids, int* flag, float* stats) {
    __shared__ int cnt, nz;
    if (threadIdx.x == 0) { cnt = 0; nz = 0; }
    __syncthreads();
    const u16* p = (const u16*)emb;
    int lc = 0, ln = 0;
    for (int k = threadIdx.x; k < 4096; k += 256) {
        int e = (p[2 * k] >> 7) & 0xFF;
        if (e >= 90 && e <= 130) lc++;
        if (ids[2 * k + 1] != 0) ln++;
    }
    atomicAdd(&cnt, lc);
    atomicAdd(&nz, ln);
    __syncthreads();
    if (threadIdx.x == 0) {
        flag[0] = (cnt < 2048) ? 1 : 0;   // 1 = floats are fp32
        flag[1] = (nz < 8) ? 1 : 0;       // 1 = ids are int64
    }
    if (threadIdx.x < 16) stats[threadIdx.x] = 0.f;
}

// ---------------- diagnostic fill (ws too small): error print reveals ws MB ---------
__global__ void diag_kernel(u16* out, int n, float val) {
    int i = blockIdx.x * 256 + threadIdx.x;
    if (i < n) out[i] = f2b(val);
}

// ---------------- weight convert: Wt[n][k] = (bf16) W[k][n] -------------------------
__global__ __launch_bounds__(256) void wt_convert(const void* __restrict__ W,
                                                  u16* __restrict__ Wt,
                                                  int K, int N,
                                                  const int* __restrict__ flagp) {
    const int f32 = flagp[0];
    __shared__ float t[32][33];
    int n0 = blockIdx.x * 32, k0 = blockIdx.y * 32;
    int c = threadIdx.x & 31, r4 = threadIdx.x >> 5;
    #pragma unroll
    for (int rr = 0; rr < 4; rr++) {
        int r = r4 * 4 + rr;
        t[r][c] = ldin(W, (size_t)(k0 + r) * N + n0 + c, f32);
    }
    __syncthreads();
    #pragma unroll
    for (int rr = 0; rr < 4; rr++) {
        int r = r4 * 4 + rr;
        Wt[(size_t)(n0 + r) * K + k0 + c] = f2b(t[c][r]);
    }
}

// ---------------- conv weight: Wc[o][k*1024+i] = (bf16) conv_w[o][i][k] -------------
__global__ __launch_bounds__(256) void convw_convert(const void* __restrict__ cw,
                                                     u16* __restrict__ Wc,
                                                     const int* __restrict__ flagp) {
    const int f32 = flagp[0];
    size_t idx = (size_t)blockIdx.x * 256 + threadIdx.x;   // < 1024*1024
    int o = idx >> 10, i = idx & 1023;
    #pragma unroll
    for (int k = 0; k < 3; k++)
        Wc[(size_t)o * 3072 + k * 1024 + i] = f2b(ldin(cw, (size_t)o * 3072 + i * 3 + k, f32));
}

// ---------------- WtBC[n][k]: rows 0..15 = fc2_w cols, 16..31 = fc3_w cols ----------
__global__ __launch_bounds__(256) void bcw_convert(const void* __restrict__ fc2_w,
                                                   const void* __restrict__ fc3_w,
                                                   u16* __restrict__ WtBC,
                                                   const int* __restrict__ flagp) {
    const int f32 = flagp[0];
    int k = blockIdx.x * 256 + threadIdx.x;    // < 1536
    int n = blockIdx.y;                        // < 32
    float v = (n < 16) ? ldin(fc2_w, (size_t)k * 16 + n, f32)
                       : ldin(fc3_w, (size_t)k * 16 + (n - 16), f32);
    WtBC[(size_t)n * DD2 + k] = f2b(v);
}

// ---------------- zero pad rows 0 and 1537 of xpTpad --------------------------------
__global__ void pad_zero_kernel(u16* xpT) {
    int i = blockIdx.x * 256 + threadIdx.x;   // < 8192
    xpT[i] = 0;
    xpT[(size_t)1537 * 8192 + i] = 0;
}

// ---------------- embedding gather -> bf16 xn + per-row partial sum/sumsq -----------
// NO atomics: 8192 blocks each write (s, ss) to partial[row] / partial[BL+row].
__global__ __launch_bounds__(256) void embed_kernel(const int* __restrict__ ids,
                                                    const void* __restrict__ emb,
                                                    u16* __restrict__ x,
                                                    float* __restrict__ partial,
                                                    const int* __restrict__ flagp) {
    const int f32 = flagp[0];
    const int i64 = flagp[1];
    int row = blockIdx.x;              // b*L + l
    int id = i64 ? ids[2 * row] : ids[row];
    u16* xr = x + (size_t)row * DD;
    float s = 0.f, ss = 0.f;
    for (int d = threadIdx.x; d < DD; d += 256) {
        float v = ldin(emb, (size_t)id * DD + d, f32);
        u16 t = f2b(v);
        xr[d] = t;
        v = bf2f(t);                   // round in-register; no global store->reload
        s += v; ss += v * v;
    }
    #pragma unroll
    for (int off = 32; off > 0; off >>= 1) {
        s  += __shfl_down(s,  off);
        ss += __shfl_down(ss, off);
    }
    __shared__ float smS[4], smQ[4];
    int lane = threadIdx.x & 63, wid = threadIdx.x >> 6;
    if (lane == 0) { smS[wid] = s; smQ[wid] = ss; }
    __syncthreads();
    if (threadIdx.x == 0) {
        partial[row]      = smS[0] + smS[1] + smS[2] + smS[3];
        partial[BL + row] = smQ[0] + smQ[1] + smQ[2] + smQ[3];
    }
}

// ---------------- reduce 1024 partials per sample -> mean, rsqrt(var) ---------------
__global__ __launch_bounds__(256) void finalize_stats_kernel(const float* __restrict__ partial,
                                                             float* __restrict__ stats) {
    int b = blockIdx.x;                        // 0..7
    const float* ps = partial + (size_t)b * 1024;
    const float* pq = partial + BL + (size_t)b * 1024;
    float s = 0.f, ss = 0.f;
    for (int i = threadIdx.x; i < 1024; i += 256) { s += ps[i]; ss += pq[i]; }
    #pragma unroll
    for (int off = 32; off > 0; off >>= 1) {
        s  += __shfl_down(s,  off);
        ss += __shfl_down(ss, off);
    }
    __shared__ float smS[4], smQ[4];
    int lane = threadIdx.x & 63, wid = threadIdx.x >> 6;
    if (lane == 0) { smS[wid] = s; smQ[wid] = ss; }
    __syncthreads();
    if (threadIdx.x == 0) {
        float S = smS[0] + smS[1] + smS[2] + smS[3];
        float Q = smQ[0] + smQ[1] + smQ[2] + smQ[3];
        const float inv = 1.f / (float)LD;
        float m = S * inv;
        float var = Q * inv - m * m;
        stats[16 + b] = m;
        stats[24 + b] = rsqrtf(var + 1e-5f);
    }
}

// ---------------- per-sample LN + RMSNorm (in place, bf16) ----------------
__global__ __launch_bounds__(256) void ln_rms_kernel(u16* __restrict__ x,
                                                     const void* __restrict__ rms_w,
                                                     const float* __restrict__ stats,
                                                     const int* __restrict__ flagp) {
    const int f32 = flagp[0];
    int row = blockIdx.x;
    int b = row >> 10;
    float m = stats[16 + b], rs = stats[24 + b];
    __shared__ float rowb[DD];
    __shared__ float sm[4];
    __shared__ float rmsv;
    u16* xr = x + (size_t)row * DD;
    float ss = 0.f;
    for (int d = threadIdx.x; d < DD; d += 256) {
        float t = (bf2f(xr[d]) - m) * rs;
        rowb[d] = t;
        ss += t * t;
    }
    #pragma unroll
    for (int off = 32; off > 0; off >>= 1) ss += __shfl_down(ss, off);
    int lane = threadIdx.x & 63, wid = threadIdx.x >> 6;
    if (lane == 0) sm[wid] = ss;
    __syncthreads();
    if (threadIdx.x == 0)
        rmsv = rsqrtf((sm[0] + sm[1] + sm[2] + sm[3]) * (1.f / (float)DD) + 1e-5f);
    __syncthreads();
    float rv = rmsv;
    for (int d = threadIdx.x; d < DD; d += 256)
        xr[d] = f2b(rowb[d] * rv * ldin(rms_w, d, f32));
}

// ---------------- MFMA GEMM: C[m][n] = act(sum_k A[m][k]*Bt[n][k] + bias) -----------
// A: bf16 [M][lda] row-major. Bt: bf16 [N][ldb] K-major (weights pre-transposed).
// 128x128 tile, BK=32, 256 threads (4 waves, 2x2), 4x4 mfma frags per wave.
// conv=1: Bt rows come from xpTpad with +tap row shift, col base = z*1024;
//         C offset = z*1024*ldc. BIAS_M: bias indexed by m (else by n).
// OUTMODE: 0 = bf16; 1 = dtype per flag (d_out).
template <int ACT, int BIAS_M, int OUTMODE>
__global__ __launch_bounds__(256) void mfma_gemm(const u16* __restrict__ A, int lda,
                                                 const u16* __restrict__ B, int ldb,
                                                 const void* __restrict__ bias,
                                                 void* __restrict__ Cout, int ldc,
                                                 int K, int conv,
                                                 const int* __restrict__ flagp) {
    const int f32 = flagp[0];
    const int tid = threadIdx.x;
    const int lane = tid & 63, wid = tid >> 6;
    const int wr = wid >> 1, wc = wid & 1;
    const int quad = lane >> 4, l16 = lane & 15;
    const int m0 = blockIdx.y << 7, n0 = blockIdx.x << 7;
    const size_t cbase = conv ? (size_t)blockIdx.z * 1024 * ldc : 0;
    const int colbase = conv ? (blockIdx.z << 10) : 0;

    __shared__ u16 As[128 * 32];
    __shared__ u16 Bs[128 * 32];

    f32x4 acc[4][4] = {};

    const int srow = tid >> 2;            // 0..63
    const int scol = (tid & 3) << 3;      // 0,8,16,24
    u16* ldsA0 = As + (size_t)(wid * 64) * 8;
    u16* ldsA1 = As + (size_t)(256 + wid * 64) * 8;
    u16* ldsB0 = Bs + (size_t)(wid * 64) * 8;
    u16* ldsB1 = Bs + (size_t)(256 + wid * 64) * 8;

    for (int k0 = 0; k0 < K; k0 += 32) {
        async_load16(A + (size_t)(m0 + srow) * lda + k0 + scol, ldsA0);
        async_load16(A + (size_t)(m0 + 64 + srow) * lda + k0 + scol, ldsA1);
        if (conv) {
            const int tap = k0 >> 10, ko = k0 & 1023;
            async_load16(B + (size_t)(n0 + srow + tap) * ldb + colbase + ko + scol, ldsB0);
            async_load16(B + (size_t)(n0 + 64 + srow + tap) * ldb + colbase + ko + scol, ldsB1);
        } else {
            async_load16(B + (size_t)(n0 + srow) * ldb + k0 + scol, ldsB0);
            async_load16(B + (size_t)(n0 + 64 + srow) * ldb + k0 + scol, ldsB1);
        }
        __syncthreads();
        short8 af[4], bf[4];
        #pragma unroll
        for (int mi = 0; mi < 4; mi++)
            af[mi] = *reinterpret_cast<const short8*>(As + (wr * 64 + mi * 16 + l16) * 32 + quad * 8);
        #pragma unroll
        for (int ni = 0; ni < 4; ni++)
            bf[ni] = *reinterpret_cast<const short8*>(Bs + (wc * 64 + ni * 16 + l16) * 32 + quad * 8);
        #pragma unroll
        for (int mi = 0; mi < 4; mi++)
            #pragma unroll
            for (int ni = 0; ni < 4; ni++)
                acc[mi][ni] = __builtin_amdgcn_mfma_f32_16x16x32_bf16(af[mi], bf[ni], acc[mi][ni], 0, 0, 0);
        __syncthreads();
    }

    #pragma unroll
    for (int mi = 0; mi < 4; mi++) {
        const int row = m0 + wr * 64 + mi * 16 + quad * 4;
        #pragma unroll
        for (int ni = 0; ni < 4; ni++) {
            const int col = n0 + wc * 64 + ni * 16 + l16;
            float bn = BIAS_M ? 0.f : ldin(bias, col, f32);
            #pragma unroll
            for (int r = 0; r < 4; r++) {
                float v = acc[mi][ni][r] + (BIAS_M ? ldin(bias, row + r, f32) : bn);
                if (ACT == 1) v = siluf(v);
                if (ACT == 2) v = softplusf(v);
                size_t ci = cbase + (size_t)(row + r) * ldc + col;
                if (OUTMODE == 1 && f32) ((float*)Cout)[ci] = v;
                else                     ((u16*)Cout)[ci] = f2b(v);
            }
        }
    }
}

// ---------------- fused Bm/Cm/s: s[row] = sum_n (xco@fc2+b2)_n * (xco@fc3+b3)_n -----
// Replaces bc_gemm_k (151 us: VALU outer-product, 128 blocks, 5.8% occupancy, 1.2M
// LDS bank conflicts, MfmaUtil 0) + s_kernel. MFMA, zero LDS, zero barriers:
// 256 blocks x 2 waves; each wave: 16 rows x 32 cols over K=1536.
// C-frag layout: col = lane&15 = n, row = quad*4 + r -> per-lane product + 16-lane
// butterfly gives s for 16 rows without materializing BC.
__global__ __launch_bounds__(128) void bcs_kernel(const u16* __restrict__ xco,
                                                  const u16* __restrict__ WtBC,
                                                  const void* __restrict__ fc2_b,
                                                  const void* __restrict__ fc3_b,
                                                  float* __restrict__ s,
                                                  const int* __restrict__ flagp) {
    const int f32 = flagp[0];
    const int lane = threadIdx.x & 63, w = threadIdx.x >> 6;
    const int l16 = lane & 15, quad = lane >> 4;
    const int row0 = blockIdx.x * 32 + w * 16;
    f32x4 acc0 = {}, acc1 = {};
    const u16* arow = xco + (size_t)(row0 + l16) * DD2 + quad * 8;
    const u16* b2r  = WtBC + (size_t)l16 * DD2 + quad * 8;
    const u16* b3r  = WtBC + (size_t)(16 + l16) * DD2 + quad * 8;
    #pragma unroll 4
    for (int k0 = 0; k0 < DD2; k0 += 32) {
        short8 af = *reinterpret_cast<const short8*>(arow + k0);
        short8 b2 = *reinterpret_cast<const short8*>(b2r + k0);
        short8 b3 = *reinterpret_cast<const short8*>(b3r + k0);
        acc0 = __builtin_amdgcn_mfma_f32_16x16x32_bf16(af, b2, acc0, 0, 0, 0);
        acc1 = __builtin_amdgcn_mfma_f32_16x16x32_bf16(af, b3, acc1, 0, 0, 0);
    }
    float bn2 = ldin(fc2_b, l16, f32);
    float bn3 = ldin(fc3_b, l16, f32);
    #pragma unroll
    for (int r = 0; r < 4; r++) {
        float p = (acc0[r] + bn2) * (acc1[r] + bn3);
        p += __shfl_xor(p, 1);
        p += __shfl_xor(p, 2);
        p += __shfl_xor(p, 4);
        p += __shfl_xor(p, 8);
        if (l16 == 0) s[row0 + quad * 4 + r] = p;
    }
}

// ---------------- z = silu(xco*delta*s) * xres   (in place over xco) -------------
__global__ void z_kernel(u16* __restrict__ xco_z,
                         const u16* __restrict__ delta,
                         const float* __restrict__ s,
                         const u16* __restrict__ xres) {
    unsigned int idx = blockIdx.x * 256u + threadIdx.x;   // < 12582912
    int row = idx / DD2;
    float y = bf2f(xco_z[idx]) * bf2f(delta[idx]) * s[row];
    xco_z[idx] = f2b(siluf(y) * bf2f(xres[idx]));
}

// ---------------- pool stage 1: per-(chunk,sample) max over PROWS rows --------------
__global__ __launch_bounds__(256) void pool1_kernel(const void* __restrict__ outp,
                                                    float* __restrict__ partial,
                                                    const int* __restrict__ flagp) {
    const int f32 = flagp[0];
    const int ch = blockIdx.x, b = blockIdx.y;
    const int l0 = ch * PROWS;
    const int t = threadIdx.x;
    float m0 = -3.4e38f, m1 = -3.4e38f, m2 = -3.4e38f;
    if (f32) {
        const float* base = (const float*)outp + (size_t)b * LD + (size_t)l0 * DD;
        for (int l = 0; l < PROWS; l++) {
            const float* row = base + (size_t)l * DD;
            m0 = fmaxf(m0, row[t]);
            m1 = fmaxf(m1, row[t + 256]);
            m2 = fmaxf(m2, row[t + 512]);
        }
    } else {
        const u16* base = (const u16*)outp + (size_t)b * LD + (size_t)l0 * DD;
        for (int l = 0; l < PROWS; l++) {
            const u16* row = base + (size_t)l * DD;
            m0 = fmaxf(m0, bf2f(row[t]));
            m1 = fmaxf(m1, bf2f(row[t + 256]));
            m2 = fmaxf(m2, bf2f(row[t + 512]));
        }
    }
    float* pp = partial + (size_t)ch * (BB * DD) + (size_t)b * DD;
    pp[t]       = m0;
    pp[t + 256] = m1;
    pp[t + 512] = m2;
}

// ---------------- pool stage 2: reduce PCH partials -> pooled row -------------------
__global__ void pool2_kernel(void* __restrict__ outp, const float* __restrict__ partial,
                             const int* __restrict__ flagp) {
    const int f32 = flagp[0];
    int idx = blockIdx.x * 256 + threadIdx.x;  // < 6144
    if (idx >= BB * DD) return;
    float m = -3.4e38f;
    #pragma unroll
    for (int ch = 0; ch < PCH; ch++)
        m = fmaxf(m, partial[(size_t)ch * (BB * DD) + idx]);
    if (f32) ((float*)outp)[(size_t)BL * DD + idx] = m;
    else     ((u16*)outp)[(size_t)BL * DD + idx] = f2b(m);
}

extern "C" void kernel_launch(void* const* d_in, const int* in_sizes, int n_in,
                              void* d_out, int out_size, void* d_ws, size_t ws_size,
                              hipStream_t stream) {
    const int*  ids    = (const int*)d_in[0];
    const void* emb    = d_in[1];
    const void* rms_w  = d_in[2];
    const void* W_in   = d_in[3];
    const void* b_in   = d_in[4];
    const void* conv_w = d_in[5];
    const void* conv_b = d_in[6];
    const void* W_cl   = d_in[7];
    const void* b_cl   = d_in[8];
    const void* fc1_w  = d_in[9];
    const void* fc1_b  = d_in[10];
    const void* fc2_w  = d_in[11];
    const void* fc2_b  = d_in[12];
    const void* fc3_w  = d_in[13];
    const void* fc3_b  = d_in[14];
    // d_in[15] = A : unused (zero initial state kills exp(delta@A) term)
    const void* W_D    = d_in[16];
    const void* b_D    = d_in[17];
    const void* W_out  = d_in[18];
    const void* b_out  = d_in[19];

    char* ws = (char*)d_ws;
    u16*   Wt_in  = (u16*)(ws);                  // [1536][768]   2,359,296
    u16*   Wt_cl  = (u16*)(ws + 2359296);        // [1536][1536]  4,718,592
    u16*   Wt_fc1 = (u16*)(ws + 7077888);        // [1536][1536]  4,718,592
    u16*   Wt_D   = (u16*)(ws + 11796480);       // [1536][768]   2,359,296
    u16*   Wt_out = (u16*)(ws + 14155776);       // [768][1536]   2,359,296
    u16*   Wc     = (u16*)(ws + 16515072);       // [1024][3072]  6,291,456 (late: WtBC)
    u16*   xpT    = (u16*)(ws + 22806528);       // [1538][8192]  25,198,592 (later: delta)
    u16*   xca    = (u16*)(ws + 48005120);       // [8192][1536]  25,165,824 (later: xres)
    u16*   xco    = (u16*)(ws + 73170944);       // [8192][1536]  25,165,824 (z in place)
    float* sbuf   = (float*)(ws + 98336768);     // 32,768
    float* stats  = (float*)(ws + 98369536);     // 128
    int*   flag   = (int*)(ws + 98369664);       // 128
    float* BC     = (float*)(ws + 98369792);     // 1,048,576 (early: stats partials; late: pool partials)
    const size_t NEED = 99418368;

    if (ws_size < NEED) {
        float v = 10000.f + (float)(ws_size >> 20);
        diag_kernel<<<(out_size + 255) / 256, 256, 0, stream>>>((u16*)d_out, out_size, v);
        return;
    }

    u16* xn    = (u16*)d_out;         // bf16 staging, dead before final GEMM
    u16* delta = xpT;                 // reuse after conv
    u16* xres  = xca;                 // reuse after xco GEMM
    u16* WtBC  = Wc;                  // reuse after conv GEMM (Wc's only reader)

    detect_kernel<<<1, 256, 0, stream>>>(emb, ids, flag, stats);
    // weight conversions (bf16, transposed to [N][K])
    wt_convert<<<dim3(1536 / 32, 768 / 32), 256, 0, stream>>>(W_in,  Wt_in,  768,  1536, flag);
    wt_convert<<<dim3(1536 / 32, 1536 / 32), 256, 0, stream>>>(W_cl,  Wt_cl,  1536, 1536, flag);
    wt_convert<<<dim3(1536 / 32, 1536 / 32), 256, 0, stream>>>(fc1_w, Wt_fc1, 1536, 1536, flag);
    wt_convert<<<dim3(1536 / 32, 768 / 32), 256, 0, stream>>>(W_D,   Wt_D,   768,  1536, flag);
    wt_convert<<<dim3(768 / 32, 1536 / 32), 256, 0, stream>>>(W_out, Wt_out, 1536, 768,  flag);
    convw_convert<<<4096, 256, 0, stream>>>(conv_w, Wc, flag);
    pad_zero_kernel<<<32, 256, 0, stream>>>(xpT);

    // embed: per-row partials into BC scratch (dead until pool), then 8-block reduce
    embed_kernel<<<BL, 256, 0, stream>>>(ids, emb, xn, BC, flag);
    finalize_stats_kernel<<<8, 256, 0, stream>>>(BC, stats);
    ln_rms_kernel<<<BL, 256, 0, stream>>>(xn, rms_w, stats, flag);

    // xpT[f+1][(b,i)] = (xn @ W_in + b_in)^T : A=Wt_in (m=f), B=xn (n=(b,i))
    mfma_gemm<0, 1, 0><<<dim3(64, 12, 1), 256, 0, stream>>>(
        Wt_in, 768, xn, 768, b_in, xpT + 8192, 8192, 768, 0, flag);
    // xca[b][o][f] = silu(conv(xp) + conv_b) : A=Wc (m=o, K=3*1024), B=xpT tap-shifted
    mfma_gemm<1, 1, 0><<<dim3(12, 8, 8), 256, 0, stream>>>(
        Wc, 3072, xpT, 8192, conv_b, xca, 1536, 3072, 1, flag);
    // Wc now dead -> build WtBC [32][1536] bf16 in its slot
    bcw_convert<<<dim3(6, 32), 256, 0, stream>>>(fc2_w, fc3_w, WtBC, flag);
    // xco = xca @ W_cl + b_cl
    mfma_gemm<0, 0, 0><<<dim3(12, 64, 1), 256, 0, stream>>>(
        xca, 1536, Wt_cl, 1536, b_cl, xco, 1536, 1536, 0, flag);
    // delta = softplus(xco @ fc1_w + fc1_b)  (into xpT slot)
    mfma_gemm<2, 0, 0><<<dim3(12, 64, 1), 256, 0, stream>>>(
        xco, 1536, Wt_fc1, 1536, fc1_b, delta, 1536, 1536, 0, flag);
    // s[row] = (xco@fc2+b2) . (xco@fc3+b3)  -- fused MFMA, no BC materialization
    bcs_kernel<<<BL / 32, 128, 0, stream>>>(xco, WtBC, fc2_b, fc3_b, sbuf, flag);
    // xres = silu(xn @ W_D + b_D)  (into xca slot)
    mfma_gemm<1, 0, 0><<<dim3(12, 64, 1), 256, 0, stream>>>(
        xn, 768, Wt_D, 768, b_D, xres, 1536, 768, 0, flag);
    // z = silu(xco * delta * s) * xres  (in place over xco)
    z_kernel<<<(BL * DD2) / 256, 256, 0, stream>>>(xco, delta, sbuf, xres);
    // out = z @ W_out + b_out -> d_out (overwrites xn staging, dead)
    mfma_gemm<0, 0, 1><<<dim3(6, 64, 1), 256, 0, stream>>>(
        xco, 1536, Wt_out, 1536, b_out, d_out, 768, 1536, 0, flag);
    // pooled = max over seq: two-stage, BC scratch
    pool1_kernel<<<dim3(PCH, BB), 256, 0, stream>>>(d_out, BC, flag);
    pool2_kernel<<<(BB * DD + 255) / 256, 256, 0, stream>>>(d_out, BC, flag);
}